// Round 1
// baseline (673.141 us; speedup 1.0000x reference)
//
#include <hip/hip_runtime.h>

// Fused persistent stacked-GRU kernel for MI355X (gfx950).
// T=512 sequential steps inside the kernel; 256 blocks x 8 batch rows; 8 waves/block.
// waves 0-3: main GRU (16 hidden units each) + gate layer (redundant)
// waves 4-7: p1/p2 GRUs (split by 16-unit halves, gate-tiles padded so acts are per-lane)

#define T_STEPS 512
#define B_BATCH 2048
#define D_IN    132
#define NROWS   8
#define NBLOCKS 256

typedef _Float16 f16x8 __attribute__((ext_vector_type(8)));
typedef float    f32x4 __attribute__((ext_vector_type(4)));
typedef float    f32x2 __attribute__((ext_vector_type(2)));

#define MFMA16(a, b, c) __builtin_amdgcn_mfma_f32_16x16x32_f16((a), (b), (c), 0, 0, 0)

// LDS tiles, each [16 rows][64 cols] fp16 = 1024 elems. dbuf stride = 1024.
#define AP1   0      // x_p1 cols 0..48                  (dbuf)
#define AP2   2048   // x_p2 cols 0..48                  (dbuf)
#define AG    4096   // [h1:0-19 h2:20-39 xg:40-47]      (dbuf)
#define AR    6144   // [g:0-15 xr:16-41]                (dbuf)
#define AP1H  8192   // h1 cols 0..19                    (dbuf)
#define AP2H  10240  // h2 cols 0..19                    (dbuf)
#define AH    12288  // h cols 0..63                     (single)
#define LDS_HALVES 13312

__device__ __forceinline__ int swz(int row, int col) {
  // XOR-swizzle 16B blocks within a 128B row to kill ds_read_b128 bank conflicts
  return row * 64 + (((col >> 3) ^ (row & 7)) << 3) + (col & 7);
}

__device__ __forceinline__ f16x8 ldsFrag(const _Float16* lds, int base, int lane, int kt) {
  int row = lane & 15;
  int blk = ((kt << 2) + (lane >> 4)) ^ (row & 7);
  return *reinterpret_cast<const f16x8*>(lds + base + row * 64 + blk * 8);
}

// B-fragment from (N,K) row-major fp32 weights: lane l supplies W[row][k], k = kbase + (l>>4)*8 + j
__device__ __forceinline__ f16x8 mkfrag(const float* W, int row, int K, int kbase, int lane, bool rowValid) {
  f16x8 f;
  int k0 = kbase + ((lane >> 4) << 3);
#pragma unroll
  for (int j = 0; j < 8; ++j) {
    int k = k0 + j;
    float v = 0.0f;
    if (rowValid && k < K) v = W[row * K + k];
    f[j] = (_Float16)v;
  }
  return f;
}

__device__ __forceinline__ float fast_rcp(float x) { return __builtin_amdgcn_rcpf(x); }

__global__ __launch_bounds__(512, 2) void rnn_fused(
    const float* __restrict__ seq,
    const float* __restrict__ p1Wih, const float* __restrict__ p1Whh,
    const float* __restrict__ p1bih, const float* __restrict__ p1bhh,
    const float* __restrict__ p2Wih, const float* __restrict__ p2Whh,
    const float* __restrict__ p2bih, const float* __restrict__ p2bhh,
    const float* __restrict__ gW,    const float* __restrict__ gb,
    const float* __restrict__ rWih,  const float* __restrict__ rWhh,
    const float* __restrict__ rbih,  const float* __restrict__ rbhh,
    float* __restrict__ out)
{
  __shared__ __align__(16) _Float16 lds[LDS_HALVES];
  const int tid  = threadIdx.x;
  const int lane = tid & 63;
  const int wv   = tid >> 6;
  const bool isR = (wv < 4);
  const int b0   = blockIdx.x * NROWS;
  const int ul   = lane & 15;
  const int rowb = (lane >> 4) * 4;           // C-frag row group (rows rowb..rowb+3)
  const float C1 = 1.44269504089f;            // log2(e)

  // ---- zero all LDS (pads rely on this) ----
  for (int i = tid; i < LDS_HALVES; i += 512) lds[i] = (_Float16)0.0f;

  // ---------------- per-role persistent state ----------------
  // main-GRU waves (0-3)
  f16x8 fghr[2], fghz[2], fghn[2], fgir[2], fgiz[2], fgin[2], fgw[2];
  float nbr2 = 0, nbz2 = 0, bin2 = 0, bhn2 = 0, gbias = 0;
  float hq[4] = {0, 0, 0, 0};
  int stAddr[3][2]; int ldIdx[3] = {0, 0, 0}; bool stOK[3] = {false, false, false};
  int uR = 0;
  // p-GRU waves (4-7)
  f16x8 pgi0[2], pgi1[2], pgi2[2], pgh0, pgh1, pgh2;
  float nbr = 0, nbz = 0, bin = 0, bhn = 0;
  float h1q[4] = {0, 0, 0, 0};
  int apB = 0, aphB = 0, gcol = 0, up = 0; bool uok = false;

  if (isR) {
    uR = wv * 16 + ul;                                   // hidden unit 0..63
    fghr[0] = mkfrag(rWhh,       uR, 64,  0, lane, true);
    fghr[1] = mkfrag(rWhh,       uR, 64, 32, lane, true);
    fghz[0] = mkfrag(rWhh,  64 + uR, 64,  0, lane, true);
    fghz[1] = mkfrag(rWhh,  64 + uR, 64, 32, lane, true);
    fghn[0] = mkfrag(rWhh, 128 + uR, 64,  0, lane, true);
    fghn[1] = mkfrag(rWhh, 128 + uR, 64, 32, lane, true);
    fgir[0] = mkfrag(rWih,       uR, 42,  0, lane, true);
    fgir[1] = mkfrag(rWih,       uR, 42, 32, lane, true);
    fgiz[0] = mkfrag(rWih,  64 + uR, 42,  0, lane, true);
    fgiz[1] = mkfrag(rWih,  64 + uR, 42, 32, lane, true);
    fgin[0] = mkfrag(rWih, 128 + uR, 42,  0, lane, true);
    fgin[1] = mkfrag(rWih, 128 + uR, 42, 32, lane, true);
    fgw[0]  = mkfrag(gW, ul, 48,  0, lane, true);
    fgw[1]  = mkfrag(gW, ul, 48, 32, lane, true);
    nbr2 = -C1 * (rbih[uR] + rbhh[uR]);
    nbz2 = -C1 * (rbih[64 + uR] + rbhh[64 + uR]);
    bin2 = rbih[128 + uR]; bhn2 = rbhh[128 + uR];
    gbias = gb[ul];
    // staging map: 528 float2 of the 8x132 slice spread across 256 r-lanes
#pragma unroll
    for (int it = 0; it < 3; ++it) {
      int ii = it * 256 + (wv * 64 + lane);
      stOK[it] = (ii < 528);
      int iic = stOK[it] ? ii : 527;
      ldIdx[it] = iic;
      int rr = iic / 66, c2 = iic % 66;
#pragma unroll
      for (int e = 0; e < 2; ++e) {
        int c = c2 * 2 + e;
        int tb, col;
        if (c < 49)       { tb = AP1; col = c; }
        else if (c < 98)  { tb = AP2; col = c - 49; }
        else if (c < 106) { tb = AG;  col = 40 + (c - 98); }
        else              { tb = AR;  col = 16 + (c - 106); }
        stAddr[it][e] = tb + swz(rr, col);
      }
    }
  } else {
    const int pw  = wv - 4;
    const int gru = pw >> 1;    // 0: p1, 1: p2
    const int s   = pw & 1;     // unit half
    const float* Wih = gru ? p2Wih : p1Wih;
    const float* Whh = gru ? p2Whh : p1Whh;
    const float* bih = gru ? p2bih : p1bih;
    const float* bhh = gru ? p2bhh : p1bhh;
    up  = s * 16 + ul;
    uok = (up < 20);
    pgi0[0] = mkfrag(Wih,      up, 49,  0, lane, uok);
    pgi0[1] = mkfrag(Wih,      up, 49, 32, lane, uok);
    pgh0    = mkfrag(Whh,      up, 20,  0, lane, uok);
    pgi1[0] = mkfrag(Wih, 20 + up, 49,  0, lane, uok);
    pgi1[1] = mkfrag(Wih, 20 + up, 49, 32, lane, uok);
    pgh1    = mkfrag(Whh, 20 + up, 20,  0, lane, uok);
    pgi2[0] = mkfrag(Wih, 40 + up, 49,  0, lane, uok);
    pgi2[1] = mkfrag(Wih, 40 + up, 49, 32, lane, uok);
    pgh2    = mkfrag(Whh, 40 + up, 20,  0, lane, uok);
    if (uok) {
      nbr = -C1 * (bih[up] + bhh[up]);
      nbz = -C1 * (bih[20 + up] + bhh[20 + up]);
      bin = bih[40 + up]; bhn = bhh[40 + up];
    }
    apB  = gru ? AP2  : AP1;
    aphB = gru ? AP2H : AP1H;
    gcol = gru ? (20 + up) : up;
  }

  __syncthreads();  // LDS zeroed before any staging writes

  // ---- prologue: stage x(0) -> buf0, prefetch x(1) -> rsB ----
  f32x2 rsA[3], rsB[3];
  if (isR) {
    const f32x2* sp0 = reinterpret_cast<const f32x2*>(seq + (size_t)b0 * D_IN);
#pragma unroll
    for (int it = 0; it < 3; ++it) rsA[it] = sp0[ldIdx[it]];
#pragma unroll
    for (int it = 0; it < 3; ++it) if (stOK[it]) {
      lds[stAddr[it][0]] = (_Float16)rsA[it][0];
      lds[stAddr[it][1]] = (_Float16)rsA[it][1];
    }
    const f32x2* sp1 = reinterpret_cast<const f32x2*>(seq + ((size_t)B_BATCH + b0) * D_IN);
#pragma unroll
    for (int it = 0; it < 3; ++it) rsB[it] = sp1[ldIdx[it]];
  }
  __syncthreads();

  auto step = [&](int t, int bfo, f32x2 (&rsNew)[3], f32x2 (&rsOld)[3]) {
    const int nbfo = bfo ^ 1024;
    f32x4 cR = {0, 0, 0, 0}, cZ = {0, 0, 0, 0}, cIN = {0, 0, 0, 0}, cHN = {0, 0, 0, 0};
    // ================= S1 =================
    if (isR) {
      // issue prefetch of x(t+2)
      int s2 = t + 2; if (s2 > T_STEPS - 1) s2 = T_STEPS - 1;
      const f32x2* sp = reinterpret_cast<const f32x2*>(seq + ((size_t)s2 * B_BATCH + b0) * D_IN);
#pragma unroll
      for (int it = 0; it < 3; ++it) rsNew[it] = sp[ldIdx[it]];
      // main-GRU hidden path: gh = h(t-1) @ rWhh^T
      f16x8 h0  = ldsFrag(lds, AH, lane, 0);
      f16x8 h1f = ldsFrag(lds, AH, lane, 1);
      cR  = MFMA16(h0, fghr[0], cR);  cR  = MFMA16(h1f, fghr[1], cR);
      cZ  = MFMA16(h0, fghz[0], cZ);  cZ  = MFMA16(h1f, fghz[1], cZ);
      cHN = MFMA16(h0, fghn[0], cHN); cHN = MFMA16(h1f, fghn[1], cHN);
      // stage x(t+1) into [nbfo] tiles
      if (t + 1 < T_STEPS) {
#pragma unroll
        for (int it = 0; it < 3; ++it) if (stOK[it]) {
          lds[nbfo + stAddr[it][0]] = (_Float16)rsOld[it][0];
          lds[nbfo + stAddr[it][1]] = (_Float16)rsOld[it][1];
        }
      }
    } else {
      // p-GRU: gi (x-path) + gh (h-path), tile-aligned gates -> per-lane activations
      f16x8 a0 = ldsFrag(lds, apB + bfo, lane, 0);
      f16x8 a1 = ldsFrag(lds, apB + bfo, lane, 1);
      f16x8 ah = ldsFrag(lds, aphB + bfo, lane, 0);
      f32x4 aR = {0, 0, 0, 0}, aZ = {0, 0, 0, 0}, aIN = {0, 0, 0, 0}, aHN = {0, 0, 0, 0};
      aR  = MFMA16(a0, pgi0[0], aR);  aR  = MFMA16(a1, pgi0[1], aR);  aR = MFMA16(ah, pgh0, aR);
      aZ  = MFMA16(a0, pgi1[0], aZ);  aZ  = MFMA16(a1, pgi1[1], aZ);  aZ = MFMA16(ah, pgh1, aZ);
      aIN = MFMA16(a0, pgi2[0], aIN); aIN = MFMA16(a1, pgi2[1], aIN);
      aHN = MFMA16(ah, pgh2, aHN);
      const bool wr = (lane < 32) && uok;
#pragma unroll
      for (int q = 0; q < 4; ++q) {
        float r  = fast_rcp(1.0f + exp2f(fmaf(aR[q], -C1, nbr)));
        float z  = fast_rcp(1.0f + exp2f(fmaf(aZ[q], -C1, nbz)));
        float pre = fmaf(r, aHN[q] + bhn, aIN[q] + bin);
        float e2 = exp2f(pre * (2.0f * C1));
        float n  = 1.0f - 2.0f * fast_rcp(1.0f + e2);
        float hv = fmaf(z, h1q[q] - n, n);
        h1q[q] = hv;
        if (wr) {
          _Float16 hh = (_Float16)hv;
          lds[AG + bfo + swz(rowb + q, gcol)] = hh;       // for gate layer (this step)
          lds[aphB + nbfo + swz(rowb + q, up)] = hh;      // for own gh (next step)
        }
      }
    }
    __syncthreads();
    // ================= S2 =================
    if (isR) {
      // gate layer (each r-wave computes it redundantly -> self-sufficient, no extra barrier)
      f16x8 g0 = ldsFrag(lds, AG + bfo, lane, 0);
      f16x8 g1 = ldsFrag(lds, AG + bfo, lane, 1);
      f32x4 cG = {0, 0, 0, 0};
      cG = MFMA16(g0, fgw[0], cG); cG = MFMA16(g1, fgw[1], cG);
      if (lane < 32) {
#pragma unroll
        for (int q = 0; q < 4; ++q) {
          float gv = fmaxf(cG[q] + gbias, 0.0f);
          lds[AR + bfo + swz(rowb + q, ul)] = (_Float16)gv;
        }
      }
      asm volatile("s_waitcnt lgkmcnt(0)" ::: "memory");
      // main-GRU input path: gi = [g, x_r] @ rWih^T
      f16x8 r0 = ldsFrag(lds, AR + bfo, lane, 0);
      f16x8 r1 = ldsFrag(lds, AR + bfo, lane, 1);
      cR  = MFMA16(r0, fgir[0], cR);  cR  = MFMA16(r1, fgir[1], cR);
      cZ  = MFMA16(r0, fgiz[0], cZ);  cZ  = MFMA16(r1, fgiz[1], cZ);
      cIN = MFMA16(r0, fgin[0], cIN); cIN = MFMA16(r1, fgin[1], cIN);
#pragma unroll
      for (int q = 0; q < 4; ++q) {
        float r  = fast_rcp(1.0f + exp2f(fmaf(cR[q], -C1, nbr2)));
        float z  = fast_rcp(1.0f + exp2f(fmaf(cZ[q], -C1, nbz2)));
        float pre = fmaf(r, cHN[q] + bhn2, cIN[q] + bin2);
        float e2 = exp2f(pre * (2.0f * C1));
        float n  = 1.0f - 2.0f * fast_rcp(1.0f + e2);
        float hv = fmaf(z, hq[q] - n, n);
        hq[q] = hv;
        if (lane < 32) {
          out[((size_t)t * B_BATCH + (size_t)(b0 + rowb + q)) * 64 + uR] = hv;
          lds[AH + swz(rowb + q, uR)] = (_Float16)hv;     // h(t) for next step's gh
        }
      }
    }
    __syncthreads();
  };

  for (int t = 0; t < T_STEPS; t += 2) {
    step(t,     0,    rsA, rsB);   // load x(t+2)->rsA, stage x(t+1) from rsB
    step(t + 1, 1024, rsB, rsA);
  }
}

extern "C" void kernel_launch(void* const* d_in, const int* in_sizes, int n_in,
                              void* d_out, int out_size, void* d_ws, size_t ws_size,
                              hipStream_t stream) {
  (void)in_sizes; (void)n_in; (void)d_ws; (void)ws_size; (void)out_size;
  const float* seq   = (const float*)d_in[0];
  const float* p1Wih = (const float*)d_in[1];
  const float* p1Whh = (const float*)d_in[2];
  const float* p1bih = (const float*)d_in[3];
  const float* p1bhh = (const float*)d_in[4];
  const float* p2Wih = (const float*)d_in[5];
  const float* p2Whh = (const float*)d_in[6];
  const float* p2bih = (const float*)d_in[7];
  const float* p2bhh = (const float*)d_in[8];
  const float* gW    = (const float*)d_in[9];
  const float* gb    = (const float*)d_in[10];
  const float* rWih  = (const float*)d_in[11];
  const float* rWhh  = (const float*)d_in[12];
  const float* rbih  = (const float*)d_in[13];
  const float* rbhh  = (const float*)d_in[14];
  float* out = (float*)d_out;
  hipLaunchKernelGGL(rnn_fused, dim3(NBLOCKS), dim3(512), 0, stream,
                     seq, p1Wih, p1Whh, p1bih, p1bhh,
                     p2Wih, p2Whh, p2bih, p2bhh,
                     gW, gb, rWih, rWhh, rbih, rbhh, out);
}